// Round 1
// 205.796 us; speedup vs baseline: 1.1105x; 1.1105x over previous
//
#include <hip/hip_runtime.h>
#include <math.h>

// Problem constants (from setup_inputs): B=2, V=10000, N=16, CIN=128, COUT=64
#define V_CNT 10000
#define NB 16
#define TQ 16          // queries per block in fold_kernel
#define BQ_TOTAL 20000 // B*V
#define NCOL 100000    // B*V*5 output columns for the final GEMM

// ws float layout:
//   [0, 2880)        W45[d][kj]     (64 x 45)
//   [2880, 2925)     Wdir9[kj]      (45)
//   [2944, 3004)     FN[f*3+axis]   (20 x 3 face normals)
//   [8192, 8192+45*100000)  PsG[kj*NCOL + col]   (TRANSPOSED: kj-major for
//                           coalesced out_kernel loads)
#define WS_W45   0
#define WS_WD9   2880
#define WS_FN    2944
#define WS_PSG   8192

// LDS row stride for Ps2: 49 words (49 % 32 == 17, odd) -> lane-stride-49
// accesses hit all 32 banks; conflict-free for both atomics and stores.
#define PSTRIDE 49

// _FTC permutation table (runtime-indexed -> device constant memory)
__device__ __constant__ int FTC_d[20][5] = {
  {1,4,0,2,3},{2,0,1,4,3},{3,1,0,4,2},{4,2,0,3,1},{0,3,1,2,4},
  {3,2,0,4,1},{4,3,0,2,1},{0,4,1,2,3},{1,0,2,4,3},{2,1,0,4,3},
  {4,0,1,3,2},{0,1,2,3,4},{1,2,0,3,4},{2,3,0,1,4},{3,4,0,1,2},
  {1,3,0,2,4},{0,2,1,3,4},{4,1,0,3,2},{3,0,1,4,2},{2,4,0,1,3}};

// color of face f = _FTC[f][0] (compile-time folded in unrolled loops)
constexpr int COLF[20] = {1,2,3,4,0,3,4,0,1,2,4,0,1,2,3,1,0,4,3,2};

// w9[k][j] = w19[W9MAP[k][j]]  (the _build_kernel row construction)
constexpr int W9MAP[9][5] = {
  {0,1,2,2,2},{3,4,5,5,5},
  {9,10,11,12,13},{9,10,12,13,11},{9,10,13,11,12},
  {14,15,16,17,18},{14,15,17,18,16},{14,15,18,16,17},
  {6,7,8,8,8}};

__device__ __constant__ int FACES_d[20][3] = {
  {1,2,7},{1,3,7},{1,3,5},{1,4,5},{1,2,4},{2,7,8},{3,7,9},{3,5,11},{4,5,6},{2,4,10},
  {2,8,10},{7,8,9},{3,9,11},{5,6,11},{4,6,10},{0,8,10},{0,6,10},{0,6,11},{0,9,11},{0,8,9}};

#define PHI_F 1.61803398874989484820f
__device__ __constant__ float VS_d[12][3] = {
  {-1.f,PHI_F,0.f},{1.f,PHI_F,0.f},{-1.f,-PHI_F,0.f},{1.f,-PHI_F,0.f},
  {0.f,-1.f,PHI_F},{0.f,1.f,PHI_F},{0.f,-1.f,-PHI_F},{0.f,1.f,-PHI_F},
  {PHI_F,0.f,-1.f},{PHI_F,0.f,1.f},{-PHI_F,0.f,-1.f},{-PHI_F,0.f,1.f}};

__device__ __forceinline__ float fast_tanh(float x){
  // |x| <= 1 here (dot of unit vectors), no overflow concerns
  float e = __expf(2.0f * x);
  return 1.0f - 2.0f * __builtin_amdgcn_rcpf(e + 1.0f);
}

// ---------------------------------------------------------------------------
// Kernel 1: weight prep. Blocks 0..63: W45[d] = w9(sum_c W[d,c,:]).
//           Block 64: Wdir9 = w9(sum_c W_dir[c,:]) + face normals.
// ---------------------------------------------------------------------------
__global__ __launch_bounds__(128) void prep_kernel(const float* __restrict__ W,
                                                   const float* __restrict__ Wdir,
                                                   float* __restrict__ ws){
  __shared__ float buf[128][20];   // pad 19->20 to break bank stride
  __shared__ float w19s[19];
  int d = blockIdx.x;   // 0..64
  int c = threadIdx.x;  // 0..127  (one per CIN)

  const float* src = (d < 64) ? (W + ((size_t)d*128 + c)*19) : (Wdir + (size_t)c*19);
  #pragma unroll
  for (int tt = 0; tt < 19; ++tt) buf[c][tt] = src[tt];

  if (d == 64 && c < 20){
    float x=0.f, y=0.f, z=0.f;
    #pragma unroll
    for (int vv=0; vv<3; ++vv){
      int vi = FACES_d[c][vv];
      x += VS_d[vi][0]; y += VS_d[vi][1]; z += VS_d[vi][2];
    }
    float inv = rsqrtf(x*x + y*y + z*z);
    ws[WS_FN + c*3 + 0] = x*inv;
    ws[WS_FN + c*3 + 1] = y*inv;
    ws[WS_FN + c*3 + 2] = z*inv;
  }
  __syncthreads();

  if (c < 19){
    float s = 0.f;
    for (int i = 0; i < 128; ++i) s += buf[i][c];
    w19s[c] = s;
  }
  __syncthreads();

  if (c < 45){
    int k = c / 5, j = c % 5;
    float v = w19s[W9MAP[k][j]];
    ws[(d < 64) ? (WS_W45 + d*45 + c) : (WS_WD9 + c)] = v;
  }
}

// ---------------------------------------------------------------------------
// Kernel 2: per block: TQ=16 queries.
//  Phase A (256 threads = 16q x 16n): gather neighbor, normalize, 20 face
//          dots -> tanh -> 5 color sums  => de5s in LDS.
//  Phase B (320 threads = 16q x 20r): per (q,r):
//          P[kj] = sum_n relu(Wdir9[k].e) * e[j],  e[j]=de5[n][FTC[r][j]].
//          k is CHUNKED 3x3 so only acc[15] is ever live (the previous
//          acc[45] exceeded the 44-VGPR allocation -> spill -> 141us at
//          13.8% VALUBusy). wdl loaded 15/chunk via uniform s_loads (SGPRs).
//          atomicAdd into Ps2[q*5+color(r)][kj]  (4-way contention, cheap).
//  Store Ps transposed to psg[kj*NCOL + col], coalesced.
// ---------------------------------------------------------------------------
__global__ __launch_bounds__(320) void fold_kernel(const int*   __restrict__ nbr,
                                                   const float* __restrict__ verts,
                                                   const float* __restrict__ ws,
                                                   float* __restrict__ psg){
  __shared__ float de5s[TQ][NB][5];        // 5120 B
  __shared__ float Ps2[TQ*5][PSTRIDE];     // 15680 B
  int t = threadIdx.x;
  int blockq0 = blockIdx.x * TQ;

  float* psf = &Ps2[0][0];
  for (int i = t; i < TQ*5*PSTRIDE; i += 320) psf[i] = 0.f;

  if (t < TQ*NB){
    int ql = t >> 4;
    int n  = t & 15;
    int qg = blockq0 + ql;                       // 0..19999
    int q  = (qg >= V_CNT) ? (qg - V_CNT) : qg;
    int b0 = qg - q;                              // 0 or 10000
    int idx = nbr[qg*NB + n];
    float vx = verts[qg*3+0], vy = verts[qg*3+1], vz = verts[qg*3+2];
    const float* nv = verts + (size_t)(b0 + idx)*3;
    float dx = nv[0]-vx, dy = nv[1]-vy, dz = nv[2]-vz;
    float dd = dx*dx + dy*dy + dz*dz;
    float inv = (dd > 0.f) ? rsqrtf(dd) : 0.f;    // ref: d/max(||d||,1e-12); exact-0 -> 0
    dx *= inv; dy *= inv; dz *= inv;
    const float* fnp = ws + WS_FN;                // uniform -> scalar loads
    float s0=0.f, s1=0.f, s2=0.f, s3=0.f, s4=0.f;
    #pragma unroll
    for (int f = 0; f < 20; ++f){
      float x = fnp[f*3+0]*dx + fnp[f*3+1]*dy + fnp[f*3+2]*dz;
      float th = fast_tanh(x);
      if      (COLF[f]==0) s0 += th;
      else if (COLF[f]==1) s1 += th;
      else if (COLF[f]==2) s2 += th;
      else if (COLF[f]==3) s3 += th;
      else                 s4 += th;
    }
    de5s[ql][n][0]=s0; de5s[ql][n][1]=s1; de5s[ql][n][2]=s2;
    de5s[ql][n][3]=s3; de5s[ql][n][4]=s4;
  }
  __syncthreads();

  {
    int ql = t / 20;
    int r  = t - ql*20;
    int f0 = FTC_d[r][0], f1 = FTC_d[r][1], f2 = FTC_d[r][2],
        f3 = FTC_d[r][3], f4 = FTC_d[r][4];
    float* pdst = &Ps2[ql*5 + f0][0];            // color(r) = FTC[r][0]
    const float* de = &de5s[ql][0][0];

    #pragma unroll 1   // keep the three acc[15] live ranges disjoint
    for (int ch = 0; ch < 3; ++ch){
      float wdl[15];
      #pragma unroll
      for (int i = 0; i < 15; ++i) wdl[i] = ws[WS_WD9 + ch*15 + i];  // uniform -> SGPR
      float acc[15];
      #pragma unroll
      for (int i = 0; i < 15; ++i) acc[i] = 0.f;

      #pragma unroll
      for (int n = 0; n < NB; ++n){
        float e0 = de[n*5 + f0];
        float e1 = de[n*5 + f1];
        float e2 = de[n*5 + f2];
        float e3 = de[n*5 + f3];
        float e4 = de[n*5 + f4];
        #pragma unroll
        for (int k3 = 0; k3 < 3; ++k3){
          float a = wdl[k3*5+0]*e0 + wdl[k3*5+1]*e1 + wdl[k3*5+2]*e2
                  + wdl[k3*5+3]*e3 + wdl[k3*5+4]*e4;
          a = fmaxf(a, 0.f);                     // relu
          acc[k3*5+0] += a * e0;
          acc[k3*5+1] += a * e1;
          acc[k3*5+2] += a * e2;
          acc[k3*5+3] += a * e3;
          acc[k3*5+4] += a * e4;
        }
      }
      #pragma unroll
      for (int i = 0; i < 15; ++i) atomicAdd(&pdst[ch*15 + i], acc[i]);
    }
  }
  __syncthreads();

  // transposed, coalesced store: psg[kj*NCOL + col], col = qg*5+s
  for (int i = t; i < 45*TQ*5; i += 320){
    int kj = i / 80;                   // 80 = TQ*5 cols per block
    int cl = i - kj*80;
    psg[(size_t)kj*NCOL + blockq0*5 + cl] = psf[cl*PSTRIDE + kj];
  }
}

// ---------------------------------------------------------------------------
// Kernel 3: out[b,d,q,s] = sum_kj W45[d][kj] * Ps[col][kj]
//  One thread per column c. psg is kj-major -> the 45 B-loads are perfectly
//  lane-coalesced. W45 row uniform -> SGPR s_loads. launch_bounds(256,4)
//  gives a 128-VGPR budget so breg[45] stays in registers (no spill).
// ---------------------------------------------------------------------------
__global__ __launch_bounds__(256, 4) void out_kernel(const float* __restrict__ ws,
                                                     const float* __restrict__ psg,
                                                     float* __restrict__ out){
  int c = blockIdx.x*256 + threadIdx.x;
  if (c >= NCOL) return;
  float breg[45];
  #pragma unroll
  for (int kj = 0; kj < 45; ++kj) breg[kj] = psg[(size_t)kj*NCOL + c];

  int b = (c >= 50000) ? 1 : 0;
  int local = c - b*50000;                         // q*5 + s
  float* ob = out + (size_t)b*3200000 + local;

  #pragma unroll 2
  for (int d = 0; d < 64; ++d){
    const float* wrow = ws + WS_W45 + d*45;        // uniform -> scalar loads
    float a0=0.f, a1=0.f, a2=0.f, a3=0.f, a4=0.f;
    #pragma unroll
    for (int kj = 0; kj < 45; kj += 5){
      a0 += wrow[kj+0]*breg[kj+0];
      a1 += wrow[kj+1]*breg[kj+1];
      a2 += wrow[kj+2]*breg[kj+2];
      a3 += wrow[kj+3]*breg[kj+3];
      a4 += wrow[kj+4]*breg[kj+4];
    }
    ob[(size_t)d*50000] = ((a0+a1)+(a2+a3))+a4;
  }
}

extern "C" void kernel_launch(void* const* d_in, const int* in_sizes, int n_in,
                              void* d_out, int out_size, void* d_ws, size_t ws_size,
                              hipStream_t stream){
  const int*   nbr   = (const int*)d_in[0];
  const float* verts = (const float*)d_in[1];
  const float* W     = (const float*)d_in[2];
  const float* Wdir  = (const float*)d_in[3];
  float* out = (float*)d_out;
  float* ws  = (float*)d_ws;           // needs ~18.1 MB scratch
  float* psg = ws + WS_PSG;

  hipLaunchKernelGGL(prep_kernel, dim3(65), dim3(128), 0, stream, W, Wdir, ws);
  hipLaunchKernelGGL(fold_kernel, dim3(BQ_TOTAL/TQ), dim3(320), 0, stream, nbr, verts, ws, psg);
  hipLaunchKernelGGL(out_kernel, dim3((NCOL+255)/256), dim3(256), 0, stream, ws, psg, out);
}

// Round 2
// 143.008 us; speedup vs baseline: 1.5981x; 1.4390x over previous
//
#include <hip/hip_runtime.h>
#include <math.h>

// Problem constants (from setup_inputs): B=2, V=10000, N=16, CIN=128, COUT=64
#define V_CNT 10000
#define NB 16
#define TQ 16          // queries per block in fold_kernel
#define BQ_TOTAL 20000 // B*V
#define NCOL 100000    // B*V*5 output columns for the final GEMM

// ws float layout:
//   [0, 2880)        W45[d][kj]     (64 x 45)
//   [2880, 2925)     Wdir9[kj]      (45)
//   [2944, 3004)     FN[f*3+axis]   (20 x 3 face normals)
//   [8192, 8192+45*100000)  PsG[kj*NCOL + col]   (TRANSPOSED: kj-major for
//                           coalesced out_kernel loads)
#define WS_W45   0
#define WS_WD9   2880
#define WS_FN    2944
#define WS_PSG   8192

// LDS row stride for Ps2: 49 words (49 % 32 == 17, odd) -> lane-stride-49
// accesses hit all 32 banks; conflict-free.
#define PSTRIDE 49

// _FTC permutation table (runtime-indexed -> device constant memory)
__device__ __constant__ int FTC_d[20][5] = {
  {1,4,0,2,3},{2,0,1,4,3},{3,1,0,4,2},{4,2,0,3,1},{0,3,1,2,4},
  {3,2,0,4,1},{4,3,0,2,1},{0,4,1,2,3},{1,0,2,4,3},{2,1,0,4,3},
  {4,0,1,3,2},{0,1,2,3,4},{1,2,0,3,4},{2,3,0,1,4},{3,4,0,1,2},
  {1,3,0,2,4},{0,2,1,3,4},{4,1,0,3,2},{3,0,1,4,2},{2,4,0,1,3}};

// faces grouped by color: RBYCOL[s][m] = m-th face r with FTC[r][0]==s.
// Phase B lane quad (4-aligned, never straddles a wave) owns color s of query q;
// the 4 members' partial sums are combined with __shfl_xor, NO LDS atomics
// (hipcc lowers LDS float atomicAdd to a CAS loop -> serial latency disaster).
__device__ __constant__ int RBYCOL_d[5][4] = {
  {4,7,11,16},{0,8,12,15},{1,9,13,19},{2,5,14,18},{3,6,10,17}};

// color of face f = _FTC[f][0] (compile-time folded in unrolled loops)
constexpr int COLF[20] = {1,2,3,4,0,3,4,0,1,2,4,0,1,2,3,1,0,4,3,2};

// w9[k][j] = w19[W9MAP[k][j]]  (the _build_kernel row construction)
constexpr int W9MAP[9][5] = {
  {0,1,2,2,2},{3,4,5,5,5},
  {9,10,11,12,13},{9,10,12,13,11},{9,10,13,11,12},
  {14,15,16,17,18},{14,15,17,18,16},{14,15,18,16,17},
  {6,7,8,8,8}};

__device__ __constant__ int FACES_d[20][3] = {
  {1,2,7},{1,3,7},{1,3,5},{1,4,5},{1,2,4},{2,7,8},{3,7,9},{3,5,11},{4,5,6},{2,4,10},
  {2,8,10},{7,8,9},{3,9,11},{5,6,11},{4,6,10},{0,8,10},{0,6,10},{0,6,11},{0,9,11},{0,8,9}};

#define PHI_F 1.61803398874989484820f
__device__ __constant__ float VS_d[12][3] = {
  {-1.f,PHI_F,0.f},{1.f,PHI_F,0.f},{-1.f,-PHI_F,0.f},{1.f,-PHI_F,0.f},
  {0.f,-1.f,PHI_F},{0.f,1.f,PHI_F},{0.f,-1.f,-PHI_F},{0.f,1.f,-PHI_F},
  {PHI_F,0.f,-1.f},{PHI_F,0.f,1.f},{-PHI_F,0.f,-1.f},{-PHI_F,0.f,1.f}};

__device__ __forceinline__ float fast_tanh(float x){
  // |x| <= 1 here (dot of unit vectors), no overflow concerns
  float e = __expf(2.0f * x);
  return 1.0f - 2.0f * __builtin_amdgcn_rcpf(e + 1.0f);
}

// ---------------------------------------------------------------------------
// Kernel 1: weight prep. Blocks 0..63: W45[d] = w9(sum_c W[d,c,:]).
//           Block 64: Wdir9 = w9(sum_c W_dir[c,:]) + face normals.
// ---------------------------------------------------------------------------
__global__ __launch_bounds__(128) void prep_kernel(const float* __restrict__ W,
                                                   const float* __restrict__ Wdir,
                                                   float* __restrict__ ws){
  __shared__ float buf[128][20];   // pad 19->20 to break bank stride
  __shared__ float w19s[19];
  int d = blockIdx.x;   // 0..64
  int c = threadIdx.x;  // 0..127  (one per CIN)

  const float* src = (d < 64) ? (W + ((size_t)d*128 + c)*19) : (Wdir + (size_t)c*19);
  #pragma unroll
  for (int tt = 0; tt < 19; ++tt) buf[c][tt] = src[tt];

  if (d == 64 && c < 20){
    float x=0.f, y=0.f, z=0.f;
    #pragma unroll
    for (int vv=0; vv<3; ++vv){
      int vi = FACES_d[c][vv];
      x += VS_d[vi][0]; y += VS_d[vi][1]; z += VS_d[vi][2];
    }
    float inv = rsqrtf(x*x + y*y + z*z);
    ws[WS_FN + c*3 + 0] = x*inv;
    ws[WS_FN + c*3 + 1] = y*inv;
    ws[WS_FN + c*3 + 2] = z*inv;
  }
  __syncthreads();

  if (c < 19){
    float s = 0.f;
    for (int i = 0; i < 128; ++i) s += buf[i][c];
    w19s[c] = s;
  }
  __syncthreads();

  if (c < 45){
    int k = c / 5, j = c % 5;
    float v = w19s[W9MAP[k][j]];
    ws[(d < 64) ? (WS_W45 + d*45 + c) : (WS_WD9 + c)] = v;
  }
}

// ---------------------------------------------------------------------------
// Kernel 2: per block: TQ=16 queries.
//  Phase A (256 threads = 16q x 16n): gather neighbor, normalize, 20 face
//          dots -> tanh -> 5 color sums  => de5s in LDS.
//  Phase B (320 threads = 16q x 5color x 4member): lane quad (ql, s, m) owns
//          face r = RBYCOL[s][m].  Per chunk of 3 k's:
//            acc[15] = sum_n relu(Wdir9[k].e)*e[j],  e[j]=de5[n][FTC[r][j]]
//          quad-reduce acc via 2x __shfl_xor; member 0 does a plain ds_write
//          (exclusive owner -> no atomics, no zero-init needed).
//  Store Ps transposed to psg[kj*NCOL + col], coalesced.
// ---------------------------------------------------------------------------
__global__ __launch_bounds__(320) void fold_kernel(const int*   __restrict__ nbr,
                                                   const float* __restrict__ verts,
                                                   const float* __restrict__ ws,
                                                   float* __restrict__ psg){
  __shared__ float de5s[TQ][NB][5];        // 5120 B
  __shared__ float Ps2[TQ*5][PSTRIDE];     // 15680 B
  int t = threadIdx.x;
  int blockq0 = blockIdx.x * TQ;

  if (t < TQ*NB){
    int ql = t >> 4;
    int n  = t & 15;
    int qg = blockq0 + ql;                       // 0..19999
    int q  = (qg >= V_CNT) ? (qg - V_CNT) : qg;
    int b0 = qg - q;                              // 0 or 10000
    int idx = nbr[qg*NB + n];
    float vx = verts[qg*3+0], vy = verts[qg*3+1], vz = verts[qg*3+2];
    const float* nv = verts + (size_t)(b0 + idx)*3;
    float dx = nv[0]-vx, dy = nv[1]-vy, dz = nv[2]-vz;
    float dd = dx*dx + dy*dy + dz*dz;
    float inv = (dd > 0.f) ? rsqrtf(dd) : 0.f;    // ref: d/max(||d||,1e-12); exact-0 -> 0
    dx *= inv; dy *= inv; dz *= inv;
    const float* fnp = ws + WS_FN;                // uniform -> scalar loads
    float s0=0.f, s1=0.f, s2=0.f, s3=0.f, s4=0.f;
    #pragma unroll
    for (int f = 0; f < 20; ++f){
      float x = fnp[f*3+0]*dx + fnp[f*3+1]*dy + fnp[f*3+2]*dz;
      float th = fast_tanh(x);
      if      (COLF[f]==0) s0 += th;
      else if (COLF[f]==1) s1 += th;
      else if (COLF[f]==2) s2 += th;
      else if (COLF[f]==3) s3 += th;
      else                 s4 += th;
    }
    de5s[ql][n][0]=s0; de5s[ql][n][1]=s1; de5s[ql][n][2]=s2;
    de5s[ql][n][3]=s3; de5s[ql][n][4]=s4;
  }
  __syncthreads();

  {
    int ql = t / 20;
    int g  = t - ql*20;          // 0..19
    int s  = g >> 2;             // color 0..4
    int m  = g & 3;              // quad member 0..3
    int r  = RBYCOL_d[s][m];     // face handled by this lane
    int f0 = FTC_d[r][0], f1 = FTC_d[r][1], f2 = FTC_d[r][2],
        f3 = FTC_d[r][3], f4 = FTC_d[r][4];     // f0 == s by construction
    float* pdst = &Ps2[ql*5 + s][0];
    const float* de = &de5s[ql][0][0];

    #pragma unroll 1   // keep the three acc[15] live ranges disjoint
    for (int ch = 0; ch < 3; ++ch){
      float wdl[15];
      #pragma unroll
      for (int i = 0; i < 15; ++i) wdl[i] = ws[WS_WD9 + ch*15 + i];  // uniform -> SGPR
      float acc[15];
      #pragma unroll
      for (int i = 0; i < 15; ++i) acc[i] = 0.f;

      #pragma unroll
      for (int n = 0; n < NB; ++n){
        float e0 = de[n*5 + f0];
        float e1 = de[n*5 + f1];
        float e2 = de[n*5 + f2];
        float e3 = de[n*5 + f3];
        float e4 = de[n*5 + f4];
        #pragma unroll
        for (int k3 = 0; k3 < 3; ++k3){
          float a = wdl[k3*5+0]*e0 + wdl[k3*5+1]*e1 + wdl[k3*5+2]*e2
                  + wdl[k3*5+3]*e3 + wdl[k3*5+4]*e4;
          a = fmaxf(a, 0.f);                     // relu
          acc[k3*5+0] += a * e0;
          acc[k3*5+1] += a * e1;
          acc[k3*5+2] += a * e2;
          acc[k3*5+3] += a * e3;
          acc[k3*5+4] += a * e4;
        }
      }
      // quad reduction across the 4 faces of this color (lanes 4-aligned,
      // masks 1,2 stay inside the quad; 64%4==0 so never cross-wave)
      #pragma unroll
      for (int i = 0; i < 15; ++i){
        acc[i] += __shfl_xor(acc[i], 1);
        acc[i] += __shfl_xor(acc[i], 2);
      }
      if (m == 0){
        #pragma unroll
        for (int i = 0; i < 15; ++i) pdst[ch*15 + i] = acc[i];
      }
    }
  }
  __syncthreads();

  // transposed, coalesced store: psg[kj*NCOL + col], col = qg*5+s
  float* psf = &Ps2[0][0];
  for (int i = t; i < 45*TQ*5; i += 320){
    int kj = i / 80;                   // 80 = TQ*5 cols per block
    int cl = i - kj*80;
    psg[(size_t)kj*NCOL + blockq0*5 + cl] = psf[cl*PSTRIDE + kj];
  }
}

// ---------------------------------------------------------------------------
// Kernel 3: out[b,d,q,s] = sum_kj W45[d][kj] * Ps[col][kj]
//  Grid (391, 2): blockIdx.y picks a 32-d half -> 782 blocks (2x occupancy,
//  half the per-wave serial chain vs one 64-d loop).
//  psg is kj-major -> the 45 B-loads are perfectly lane-coalesced.
//  W45 row uniform -> SGPR s_loads.
// ---------------------------------------------------------------------------
__global__ __launch_bounds__(256, 4) void out_kernel(const float* __restrict__ ws,
                                                     const float* __restrict__ psg,
                                                     float* __restrict__ out){
  int c = blockIdx.x*256 + threadIdx.x;
  if (c >= NCOL) return;
  float breg[45];
  #pragma unroll
  for (int kj = 0; kj < 45; ++kj) breg[kj] = psg[(size_t)kj*NCOL + c];

  int b = (c >= 50000) ? 1 : 0;
  int local = c - b*50000;                         // q*5 + s
  int d0 = blockIdx.y * 32;
  float* ob = out + (size_t)b*3200000 + local;

  #pragma unroll 2
  for (int dd = 0; dd < 32; ++dd){
    int d = d0 + dd;
    const float* wrow = ws + WS_W45 + d*45;        // uniform -> scalar loads
    float a0=0.f, a1=0.f, a2=0.f, a3=0.f, a4=0.f;
    #pragma unroll
    for (int kj = 0; kj < 45; kj += 5){
      a0 += wrow[kj+0]*breg[kj+0];
      a1 += wrow[kj+1]*breg[kj+1];
      a2 += wrow[kj+2]*breg[kj+2];
      a3 += wrow[kj+3]*breg[kj+3];
      a4 += wrow[kj+4]*breg[kj+4];
    }
    ob[(size_t)d*50000] = ((a0+a1)+(a2+a3))+a4;
  }
}

extern "C" void kernel_launch(void* const* d_in, const int* in_sizes, int n_in,
                              void* d_out, int out_size, void* d_ws, size_t ws_size,
                              hipStream_t stream){
  const int*   nbr   = (const int*)d_in[0];
  const float* verts = (const float*)d_in[1];
  const float* W     = (const float*)d_in[2];
  const float* Wdir  = (const float*)d_in[3];
  float* out = (float*)d_out;
  float* ws  = (float*)d_ws;           // needs ~18.1 MB scratch
  float* psg = ws + WS_PSG;

  hipLaunchKernelGGL(prep_kernel, dim3(65), dim3(128), 0, stream, W, Wdir, ws);
  hipLaunchKernelGGL(fold_kernel, dim3(BQ_TOTAL/TQ), dim3(320), 0, stream, nbr, verts, ws, psg);
  hipLaunchKernelGGL(out_kernel, dim3((NCOL+255)/256, 2), dim3(256), 0, stream, ws, psg, out);
}

// Round 3
// 105.890 us; speedup vs baseline: 2.1583x; 1.3505x over previous
//
#include <hip/hip_runtime.h>
#include <math.h>

// Problem constants (from setup_inputs): B=2, V=10000, N=16, CIN=128, COUT=64
#define V_CNT 10000
#define NB 16
#define TQ 16          // queries per block in fold_kernel
#define BQ_TOTAL 20000 // B*V

// ws float layout (weight scratch only; psg is GONE - GEMM fused into fold):
//   [0, 2880)        W45[d][kj]     (64 x 45)
//   [2880, 2925)     Wdir9[kj]      (45)
//   [2944, 3004)     FN[f*3+axis]   (20 x 3 face normals)
#define WS_W45   0
#define WS_WD9   2880
#define WS_FN    2944

// Ps2T LDS row stride: 84 words = 336 B = 21*16 -> float4-aligned rows;
// Phase-B writers (16 lanes/wave, distinct cols) hit distinct banks.
#define PST 84

// _FTC permutation table (runtime-indexed -> device constant memory)
__device__ __constant__ int FTC_d[20][5] = {
  {1,4,0,2,3},{2,0,1,4,3},{3,1,0,4,2},{4,2,0,3,1},{0,3,1,2,4},
  {3,2,0,4,1},{4,3,0,2,1},{0,4,1,2,3},{1,0,2,4,3},{2,1,0,4,3},
  {4,0,1,3,2},{0,1,2,3,4},{1,2,0,3,4},{2,3,0,1,4},{3,4,0,1,2},
  {1,3,0,2,4},{0,2,1,3,4},{4,1,0,3,2},{3,0,1,4,2},{2,4,0,1,3}};

// faces grouped by color: RBYCOL[s][m] = m-th face r with FTC[r][0]==s.
// Phase B lane quad (4-aligned, never straddles a wave) owns color s of query q;
// the 4 members' partial sums are combined with __shfl_xor (no LDS atomics).
__device__ __constant__ int RBYCOL_d[5][4] = {
  {4,7,11,16},{0,8,12,15},{1,9,13,19},{2,5,14,18},{3,6,10,17}};

// color of face f = _FTC[f][0] (compile-time folded in unrolled loops)
constexpr int COLF[20] = {1,2,3,4,0,3,4,0,1,2,4,0,1,2,3,1,0,4,3,2};

// w9[k][j] = w19[W9MAP[k][j]]  (the _build_kernel row construction)
constexpr int W9MAP[9][5] = {
  {0,1,2,2,2},{3,4,5,5,5},
  {9,10,11,12,13},{9,10,12,13,11},{9,10,13,11,12},
  {14,15,16,17,18},{14,15,17,18,16},{14,15,18,16,17},
  {6,7,8,8,8}};

__device__ __constant__ int FACES_d[20][3] = {
  {1,2,7},{1,3,7},{1,3,5},{1,4,5},{1,2,4},{2,7,8},{3,7,9},{3,5,11},{4,5,6},{2,4,10},
  {2,8,10},{7,8,9},{3,9,11},{5,6,11},{4,6,10},{0,8,10},{0,6,10},{0,6,11},{0,9,11},{0,8,9}};

#define PHI_F 1.61803398874989484820f
__device__ __constant__ float VS_d[12][3] = {
  {-1.f,PHI_F,0.f},{1.f,PHI_F,0.f},{-1.f,-PHI_F,0.f},{1.f,-PHI_F,0.f},
  {0.f,-1.f,PHI_F},{0.f,1.f,PHI_F},{0.f,-1.f,-PHI_F},{0.f,1.f,-PHI_F},
  {PHI_F,0.f,-1.f},{PHI_F,0.f,1.f},{-PHI_F,0.f,-1.f},{-PHI_F,0.f,1.f}};

__device__ __forceinline__ float fast_tanh(float x){
  // |x| <= 1 here (dot of unit vectors), no overflow concerns
  float e = __expf(2.0f * x);
  return 1.0f - 2.0f * __builtin_amdgcn_rcpf(e + 1.0f);
}

// ---------------------------------------------------------------------------
// Kernel 1: weight prep. Blocks 0..63: W45[d] = w9(sum_c W[d,c,:]).
//           Block 64: Wdir9 = w9(sum_c W_dir[c,:]) + face normals.
// ---------------------------------------------------------------------------
__global__ __launch_bounds__(128) void prep_kernel(const float* __restrict__ W,
                                                   const float* __restrict__ Wdir,
                                                   float* __restrict__ ws){
  __shared__ float buf[128][20];   // pad 19->20 to break bank stride
  __shared__ float w19s[19];
  int d = blockIdx.x;   // 0..64
  int c = threadIdx.x;  // 0..127  (one per CIN)

  const float* src = (d < 64) ? (W + ((size_t)d*128 + c)*19) : (Wdir + (size_t)c*19);
  #pragma unroll
  for (int tt = 0; tt < 19; ++tt) buf[c][tt] = src[tt];

  if (d == 64 && c < 20){
    float x=0.f, y=0.f, z=0.f;
    #pragma unroll
    for (int vv=0; vv<3; ++vv){
      int vi = FACES_d[c][vv];
      x += VS_d[vi][0]; y += VS_d[vi][1]; z += VS_d[vi][2];
    }
    float inv = rsqrtf(x*x + y*y + z*z);
    ws[WS_FN + c*3 + 0] = x*inv;
    ws[WS_FN + c*3 + 1] = y*inv;
    ws[WS_FN + c*3 + 2] = z*inv;
  }
  __syncthreads();

  if (c < 19){
    float s = 0.f;
    for (int i = 0; i < 128; ++i) s += buf[i][c];
    w19s[c] = s;
  }
  __syncthreads();

  if (c < 45){
    int k = c / 5, j = c % 5;
    float v = w19s[W9MAP[k][j]];
    ws[(d < 64) ? (WS_W45 + d*45 + c) : (WS_WD9 + c)] = v;
  }
}

// ---------------------------------------------------------------------------
// Kernel 2 (fused): per block: TQ=16 queries -> FINAL output (no psg, no
// third kernel).
//  Stage0 (all 320): W45 (64x45) -> LDS transposed W45T[kj][d].
//  Phase A (256 thr = 16q x 16n): gather neighbor, normalize, 20 face dots
//          -> tanh -> 5 color sums  => de5s in LDS.
//  Phase B (320 thr = 16q x 5color x 4member): lane quad (ql,s,m) owns face
//          r=RBYCOL[s][m].  SINGLE pass over n with acc[45] live (the 3-chunk
//          split was a spill workaround for the old 44-VGPR budget; at
//          VGPR=128 it just tripled the e-loads and reduces):
//            acc[kj] += relu(Wdir9[k].e)*e[j],  e[j]=de5[n][FTC[r][j]]
//          quad-reduce via 2x __shfl_xor; m==0 writes col to Ps2T[kj][col].
//  Phase C (320 thr = 16 dquad x 20 colquad): 64x45 @ 45x80 GEMM from LDS,
//          4x4 register tile, float4 reads; store out[b,d,col] directly.
// ---------------------------------------------------------------------------
__global__ __launch_bounds__(320) void fold_kernel(const int*   __restrict__ nbr,
                                                   const float* __restrict__ verts,
                                                   const float* __restrict__ ws,
                                                   float* __restrict__ out){
  __shared__ float de5s[TQ][NB][5];        // 5120 B
  __shared__ float Ps2T[45][PST];          // 15120 B  [kj][col]
  __shared__ float W45T[45][64];           // 11520 B  [kj][d]
  int t = threadIdx.x;
  int blockq0 = blockIdx.x * TQ;

  // ---- Stage0: W45 -> W45T (2880 = 320*9, coalesced global reads) ----
  #pragma unroll
  for (int sW = 0; sW < 9; ++sW){
    int i  = t + sW*320;
    int d  = i / 45;
    int kj = i - d*45;
    W45T[kj][d] = ws[WS_W45 + i];
  }

  // ---- Phase A ----
  if (t < TQ*NB){
    int ql = t >> 4;
    int n  = t & 15;
    int qg = blockq0 + ql;                       // 0..19999
    int q  = (qg >= V_CNT) ? (qg - V_CNT) : qg;
    int b0 = qg - q;                              // 0 or 10000
    int idx = nbr[qg*NB + n];
    float vx = verts[qg*3+0], vy = verts[qg*3+1], vz = verts[qg*3+2];
    const float* nv = verts + (size_t)(b0 + idx)*3;
    float dx = nv[0]-vx, dy = nv[1]-vy, dz = nv[2]-vz;
    float dd = dx*dx + dy*dy + dz*dz;
    float inv = (dd > 0.f) ? rsqrtf(dd) : 0.f;    // ref: d/max(||d||,1e-12); exact-0 -> 0
    dx *= inv; dy *= inv; dz *= inv;
    const float* fnp = ws + WS_FN;                // uniform -> scalar loads
    float s0=0.f, s1=0.f, s2=0.f, s3=0.f, s4=0.f;
    #pragma unroll
    for (int f = 0; f < 20; ++f){
      float x = fnp[f*3+0]*dx + fnp[f*3+1]*dy + fnp[f*3+2]*dz;
      float th = fast_tanh(x);
      if      (COLF[f]==0) s0 += th;
      else if (COLF[f]==1) s1 += th;
      else if (COLF[f]==2) s2 += th;
      else if (COLF[f]==3) s3 += th;
      else                 s4 += th;
    }
    de5s[ql][n][0]=s0; de5s[ql][n][1]=s1; de5s[ql][n][2]=s2;
    de5s[ql][n][3]=s3; de5s[ql][n][4]=s4;
  }
  __syncthreads();

  // ---- Phase B ----
  {
    int ql = t / 20;
    int g  = t - ql*20;          // 0..19
    int s  = g >> 2;             // color 0..4
    int m  = g & 3;              // quad member 0..3
    int r  = RBYCOL_d[s][m];     // face handled by this lane
    int f0 = FTC_d[r][0], f1 = FTC_d[r][1], f2 = FTC_d[r][2],
        f3 = FTC_d[r][3], f4 = FTC_d[r][4];     // f0 == s by construction
    const float* de = &de5s[ql][0][0];

    float wdl[45];
    #pragma unroll
    for (int i = 0; i < 45; ++i) wdl[i] = ws[WS_WD9 + i];  // uniform -> SGPR
    float acc[45];
    #pragma unroll
    for (int i = 0; i < 45; ++i) acc[i] = 0.f;

    #pragma unroll
    for (int n = 0; n < NB; ++n){
      float e0 = de[n*5 + f0];
      float e1 = de[n*5 + f1];
      float e2 = de[n*5 + f2];
      float e3 = de[n*5 + f3];
      float e4 = de[n*5 + f4];
      #pragma unroll
      for (int k = 0; k < 9; ++k){
        float a = wdl[k*5+0]*e0 + wdl[k*5+1]*e1 + wdl[k*5+2]*e2
                + wdl[k*5+3]*e3 + wdl[k*5+4]*e4;
        a = fmaxf(a, 0.f);                       // relu
        acc[k*5+0] += a * e0;
        acc[k*5+1] += a * e1;
        acc[k*5+2] += a * e2;
        acc[k*5+3] += a * e3;
        acc[k*5+4] += a * e4;
      }
    }
    // quad reduction across the 4 faces of this color (lanes 4-aligned,
    // masks 1,2 stay inside the quad; 64%4==0 so never cross-wave)
    #pragma unroll
    for (int i = 0; i < 45; ++i){
      acc[i] += __shfl_xor(acc[i], 1);
      acc[i] += __shfl_xor(acc[i], 2);
    }
    if (m == 0){
      int col = ql*5 + s;
      #pragma unroll
      for (int i = 0; i < 45; ++i) Ps2T[i][col] = acc[i];
    }
  }
  __syncthreads();

  // ---- Phase C: out[d, col] = sum_kj W45T[kj][d] * Ps2T[kj][col] ----
  {
    int dq = t / 20;             // 0..15 -> d0 = dq*4
    int cq = t - dq*20;          // 0..19 -> col0 = cq*4 (inner for coalescing)
    float a00=0,a01=0,a02=0,a03=0, a10=0,a11=0,a12=0,a13=0,
          a20=0,a21=0,a22=0,a23=0, a30=0,a31=0,a32=0,a33=0;
    #pragma unroll 5
    for (int kj = 0; kj < 45; ++kj){
      float4 w = *(const float4*)&W45T[kj][dq*4];
      float4 p = *(const float4*)&Ps2T[kj][cq*4];
      a00 += w.x*p.x; a01 += w.x*p.y; a02 += w.x*p.z; a03 += w.x*p.w;
      a10 += w.y*p.x; a11 += w.y*p.y; a12 += w.y*p.z; a13 += w.y*p.w;
      a20 += w.z*p.x; a21 += w.z*p.y; a22 += w.z*p.z; a23 += w.z*p.w;
      a30 += w.w*p.x; a31 += w.w*p.y; a32 += w.w*p.z; a33 += w.w*p.w;
    }
    int b   = (blockq0 >= V_CNT) ? 1 : 0;
    int lq0 = blockq0 - b*V_CNT;
    float* ob = out + (size_t)b*3200000 + (size_t)lq0*5 + cq*4;
    int d0 = dq*4;
    *(float4*)&ob[(size_t)(d0+0)*50000] = make_float4(a00,a01,a02,a03);
    *(float4*)&ob[(size_t)(d0+1)*50000] = make_float4(a10,a11,a12,a13);
    *(float4*)&ob[(size_t)(d0+2)*50000] = make_float4(a20,a21,a22,a23);
    *(float4*)&ob[(size_t)(d0+3)*50000] = make_float4(a30,a31,a32,a33);
  }
}

extern "C" void kernel_launch(void* const* d_in, const int* in_sizes, int n_in,
                              void* d_out, int out_size, void* d_ws, size_t ws_size,
                              hipStream_t stream){
  const int*   nbr   = (const int*)d_in[0];
  const float* verts = (const float*)d_in[1];
  const float* W     = (const float*)d_in[2];
  const float* Wdir  = (const float*)d_in[3];
  float* out = (float*)d_out;
  float* ws  = (float*)d_ws;           // ~12 KB weight scratch

  hipLaunchKernelGGL(prep_kernel, dim3(65), dim3(128), 0, stream, W, Wdir, ws);
  hipLaunchKernelGGL(fold_kernel, dim3(BQ_TOTAL/TQ), dim3(320), 0, stream, nbr, verts, ws, out);
}

// Round 4
// 100.437 us; speedup vs baseline: 2.2754x; 1.0543x over previous
//
#include <hip/hip_runtime.h>
#include <math.h>

// Problem constants (from setup_inputs): B=2, V=10000, N=16, CIN=128, COUT=64
#define V_CNT 10000
#define NB 16
#define TQ 16          // queries per block in fold_kernel
#define BQ_TOTAL 20000 // B*V

// ws float layout (weight scratch only):
//   [0, 2880)        W45T[kj][d]    (45 x 64, kj-major, float4-aligned rows)
//                    -> Phase C reads this straight from global: 4 distinct
//                       16B addrs/wave/instr, L1-broadcast. Keeping it in LDS
//                       cost 11.5KB/block and capped occupancy at 5 blocks/CU.
//   [2880, 2925)     Wdir9[kj]      (45)
//   [2944, 3004)     FN[f*3+axis]   (20 x 3 face normals)
#define WS_W45T  0
#define WS_WD9   2880
#define WS_FN    2944

// Ps2T LDS row stride: 84 words = 336 B = 21*16 -> float4-aligned rows.
#define PST 84

// _FTC permutation table (runtime-indexed -> device constant memory)
__device__ __constant__ int FTC_d[20][5] = {
  {1,4,0,2,3},{2,0,1,4,3},{3,1,0,4,2},{4,2,0,3,1},{0,3,1,2,4},
  {3,2,0,4,1},{4,3,0,2,1},{0,4,1,2,3},{1,0,2,4,3},{2,1,0,4,3},
  {4,0,1,3,2},{0,1,2,3,4},{1,2,0,3,4},{2,3,0,1,4},{3,4,0,1,2},
  {1,3,0,2,4},{0,2,1,3,4},{4,1,0,3,2},{3,0,1,4,2},{2,4,0,1,3}};

// faces grouped by color: RBYCOL[s][m] = m-th face r with FTC[r][0]==s.
// Phase B lane quad (4-aligned, never straddles a wave) owns color s of query q;
// the 4 members' partial sums are combined with __shfl_xor (no LDS atomics).
__device__ __constant__ int RBYCOL_d[5][4] = {
  {4,7,11,16},{0,8,12,15},{1,9,13,19},{2,5,14,18},{3,6,10,17}};

// color of face f = _FTC[f][0] (compile-time folded in unrolled loops)
constexpr int COLF[20] = {1,2,3,4,0,3,4,0,1,2,4,0,1,2,3,1,0,4,3,2};

// w9[k][j] = w19[W9MAP[k][j]]  (the _build_kernel row construction)
constexpr int W9MAP[9][5] = {
  {0,1,2,2,2},{3,4,5,5,5},
  {9,10,11,12,13},{9,10,12,13,11},{9,10,13,11,12},
  {14,15,16,17,18},{14,15,17,18,16},{14,15,18,16,17},
  {6,7,8,8,8}};

__device__ __constant__ int FACES_d[20][3] = {
  {1,2,7},{1,3,7},{1,3,5},{1,4,5},{1,2,4},{2,7,8},{3,7,9},{3,5,11},{4,5,6},{2,4,10},
  {2,8,10},{7,8,9},{3,9,11},{5,6,11},{4,6,10},{0,8,10},{0,6,10},{0,6,11},{0,9,11},{0,8,9}};

#define PHI_F 1.61803398874989484820f
__device__ __constant__ float VS_d[12][3] = {
  {-1.f,PHI_F,0.f},{1.f,PHI_F,0.f},{-1.f,-PHI_F,0.f},{1.f,-PHI_F,0.f},
  {0.f,-1.f,PHI_F},{0.f,1.f,PHI_F},{0.f,-1.f,-PHI_F},{0.f,1.f,-PHI_F},
  {PHI_F,0.f,-1.f},{PHI_F,0.f,1.f},{-PHI_F,0.f,-1.f},{-PHI_F,0.f,1.f}};

__device__ __forceinline__ float fast_tanh(float x){
  // |x| <= 1 here (dot of unit vectors), no overflow concerns
  float e = __expf(2.0f * x);
  return 1.0f - 2.0f * __builtin_amdgcn_rcpf(e + 1.0f);
}

// ---------------------------------------------------------------------------
// Kernel 1: weight prep. Blocks 0..63: W45T[.][d] = w9(sum_c W[d,c,:]),
//           written TRANSPOSED (kj-major) so fold Phase C gets float4 rows.
//           Block 64: Wdir9 = w9(sum_c W_dir[c,:]) + face normals.
// ---------------------------------------------------------------------------
__global__ __launch_bounds__(128) void prep_kernel(const float* __restrict__ W,
                                                   const float* __restrict__ Wdir,
                                                   float* __restrict__ ws){
  __shared__ float buf[128][20];   // pad 19->20 to break bank stride
  __shared__ float w19s[19];
  int d = blockIdx.x;   // 0..64
  int c = threadIdx.x;  // 0..127  (one per CIN)

  const float* src = (d < 64) ? (W + ((size_t)d*128 + c)*19) : (Wdir + (size_t)c*19);
  #pragma unroll
  for (int tt = 0; tt < 19; ++tt) buf[c][tt] = src[tt];

  if (d == 64 && c < 20){
    float x=0.f, y=0.f, z=0.f;
    #pragma unroll
    for (int vv=0; vv<3; ++vv){
      int vi = FACES_d[c][vv];
      x += VS_d[vi][0]; y += VS_d[vi][1]; z += VS_d[vi][2];
    }
    float inv = rsqrtf(x*x + y*y + z*z);
    ws[WS_FN + c*3 + 0] = x*inv;
    ws[WS_FN + c*3 + 1] = y*inv;
    ws[WS_FN + c*3 + 2] = z*inv;
  }
  __syncthreads();

  if (c < 19){
    float s = 0.f;
    for (int i = 0; i < 128; ++i) s += buf[i][c];
    w19s[c] = s;
  }
  __syncthreads();

  if (c < 45){
    int k = c / 5, j = c % 5;
    float v = w19s[W9MAP[k][j]];
    if (d < 64) ws[WS_W45T + c*64 + d] = v;     // transposed [kj][d]
    else        ws[WS_WD9  + c]        = v;
  }
}

// ---------------------------------------------------------------------------
// Kernel 2 (fused): per block: TQ=16 queries -> FINAL output.
//  Phase A (256 thr = 16q x 16n): gather neighbor, normalize, 20 face dots
//          -> tanh -> 5 color sums  => de5s in LDS.
//  Phase B (320 thr = 16q x 5color x 4member): lane quad (ql,s,m) owns face
//          r=RBYCOL[s][m]; acc[45] over n; quad-reduce via 2x __shfl_xor;
//          m==0 writes col to Ps2T[kj][col].
//  Phase C (320 thr = 16 dquad x 20 colquad): 64x45 @ 45x80 GEMM;
//          W from GLOBAL (L1-broadcast, 4 distinct addrs/wave), Ps from LDS;
//          4x4 register tile; float4 stores along col.
//  LDS = 20.2KB -> 6 blocks/CU resident (was 31.5KB -> 5).
// ---------------------------------------------------------------------------
__global__ __launch_bounds__(320) void fold_kernel(const int*   __restrict__ nbr,
                                                   const float* __restrict__ verts,
                                                   const float* __restrict__ ws,
                                                   float* __restrict__ out){
  __shared__ float de5s[TQ][NB][5];        // 5120 B
  __shared__ float Ps2T[45][PST];          // 15120 B  [kj][col]
  int t = threadIdx.x;
  int blockq0 = blockIdx.x * TQ;

  // ---- Phase A ----
  if (t < TQ*NB){
    int ql = t >> 4;
    int n  = t & 15;
    int qg = blockq0 + ql;                       // 0..19999
    int q  = (qg >= V_CNT) ? (qg - V_CNT) : qg;
    int b0 = qg - q;                              // 0 or 10000
    int idx = nbr[qg*NB + n];
    float vx = verts[qg*3+0], vy = verts[qg*3+1], vz = verts[qg*3+2];
    const float* nv = verts + (size_t)(b0 + idx)*3;
    float dx = nv[0]-vx, dy = nv[1]-vy, dz = nv[2]-vz;
    float dd = dx*dx + dy*dy + dz*dz;
    float inv = (dd > 0.f) ? rsqrtf(dd) : 0.f;    // ref: d/max(||d||,1e-12); exact-0 -> 0
    dx *= inv; dy *= inv; dz *= inv;
    const float* fnp = ws + WS_FN;                // uniform -> scalar loads
    float s0=0.f, s1=0.f, s2=0.f, s3=0.f, s4=0.f;
    #pragma unroll
    for (int f = 0; f < 20; ++f){
      float x = fnp[f*3+0]*dx + fnp[f*3+1]*dy + fnp[f*3+2]*dz;
      float th = fast_tanh(x);
      if      (COLF[f]==0) s0 += th;
      else if (COLF[f]==1) s1 += th;
      else if (COLF[f]==2) s2 += th;
      else if (COLF[f]==3) s3 += th;
      else                 s4 += th;
    }
    de5s[ql][n][0]=s0; de5s[ql][n][1]=s1; de5s[ql][n][2]=s2;
    de5s[ql][n][3]=s3; de5s[ql][n][4]=s4;
  }
  __syncthreads();

  // ---- Phase B ----
  {
    int ql = t / 20;
    int g  = t - ql*20;          // 0..19
    int s  = g >> 2;             // color 0..4
    int m  = g & 3;              // quad member 0..3
    int r  = RBYCOL_d[s][m];     // face handled by this lane
    int f0 = FTC_d[r][0], f1 = FTC_d[r][1], f2 = FTC_d[r][2],
        f3 = FTC_d[r][3], f4 = FTC_d[r][4];     // f0 == s by construction
    const float* de = &de5s[ql][0][0];

    float wdl[45];
    #pragma unroll
    for (int i = 0; i < 45; ++i) wdl[i] = ws[WS_WD9 + i];  // uniform -> SGPR
    float acc[45];
    #pragma unroll
    for (int i = 0; i < 45; ++i) acc[i] = 0.f;

    #pragma unroll
    for (int n = 0; n < NB; ++n){
      float e0 = de[n*5 + f0];
      float e1 = de[n*5 + f1];
      float e2 = de[n*5 + f2];
      float e3 = de[n*5 + f3];
      float e4 = de[n*5 + f4];
      #pragma unroll
      for (int k = 0; k < 9; ++k){
        float a = wdl[k*5+0]*e0 + wdl[k*5+1]*e1 + wdl[k*5+2]*e2
                + wdl[k*5+3]*e3 + wdl[k*5+4]*e4;
        a = fmaxf(a, 0.f);                       // relu
        acc[k*5+0] += a * e0;
        acc[k*5+1] += a * e1;
        acc[k*5+2] += a * e2;
        acc[k*5+3] += a * e3;
        acc[k*5+4] += a * e4;
      }
    }
    // quad reduction across the 4 faces of this color (lanes 4-aligned,
    // masks 1,2 stay inside the quad; 64%4==0 so never cross-wave)
    #pragma unroll
    for (int i = 0; i < 45; ++i){
      acc[i] += __shfl_xor(acc[i], 1);
      acc[i] += __shfl_xor(acc[i], 2);
    }
    if (m == 0){
      int col = ql*5 + s;
      #pragma unroll
      for (int i = 0; i < 45; ++i) Ps2T[i][col] = acc[i];
    }
  }
  __syncthreads();

  // ---- Phase C: out[d, col] = sum_kj W45T[kj][d] * Ps2T[kj][col] ----
  {
    int dq = t / 20;             // 0..15 -> d0 = dq*4
    int cq = t - dq*20;          // 0..19 -> col0 = cq*4 (inner for coalescing)
    const float* wg = ws + WS_W45T + dq*4;       // global, L1-broadcast
    float a00=0,a01=0,a02=0,a03=0, a10=0,a11=0,a12=0,a13=0,
          a20=0,a21=0,a22=0,a23=0, a30=0,a31=0,a32=0,a33=0;
    #pragma unroll 5
    for (int kj = 0; kj < 45; ++kj){
      float4 w = *(const float4*)&wg[kj*64];
      float4 p = *(const float4*)&Ps2T[kj][cq*4];
      a00 += w.x*p.x; a01 += w.x*p.y; a02 += w.x*p.z; a03 += w.x*p.w;
      a10 += w.y*p.x; a11 += w.y*p.y; a12 += w.y*p.z; a13 += w.y*p.w;
      a20 += w.z*p.x; a21 += w.z*p.y; a22 += w.z*p.z; a23 += w.z*p.w;
      a30 += w.w*p.x; a31 += w.w*p.y; a32 += w.w*p.z; a33 += w.w*p.w;
    }
    int b   = (blockq0 >= V_CNT) ? 1 : 0;
    int lq0 = blockq0 - b*V_CNT;
    float* ob = out + (size_t)b*3200000 + (size_t)lq0*5 + cq*4;
    int d0 = dq*4;
    *(float4*)&ob[(size_t)(d0+0)*50000] = make_float4(a00,a01,a02,a03);
    *(float4*)&ob[(size_t)(d0+1)*50000] = make_float4(a10,a11,a12,a13);
    *(float4*)&ob[(size_t)(d0+2)*50000] = make_float4(a20,a21,a22,a23);
    *(float4*)&ob[(size_t)(d0+3)*50000] = make_float4(a30,a31,a32,a33);
  }
}

extern "C" void kernel_launch(void* const* d_in, const int* in_sizes, int n_in,
                              void* d_out, int out_size, void* d_ws, size_t ws_size,
                              hipStream_t stream){
  const int*   nbr   = (const int*)d_in[0];
  const float* verts = (const float*)d_in[1];
  const float* W     = (const float*)d_in[2];
  const float* Wdir  = (const float*)d_in[3];
  float* out = (float*)d_out;
  float* ws  = (float*)d_ws;           // ~12 KB weight scratch

  hipLaunchKernelGGL(prep_kernel, dim3(65), dim3(128), 0, stream, W, Wdir, ws);
  hipLaunchKernelGGL(fold_kernel, dim3(BQ_TOTAL/TQ), dim3(320), 0, stream, nbr, verts, ws, out);
}